// Round 10
// baseline (659.794 us; speedup 1.0000x reference)
//
#include <hip/hip_runtime.h>

#define SCALE 0.17677669529663687f

typedef __attribute__((ext_vector_type(8))) short short8;
typedef __attribute__((ext_vector_type(4))) float f32x4;
typedef __attribute__((ext_vector_type(4))) _Float16 half4;

__device__ __forceinline__ f32x4 MFMA32(short8 a, short8 b, f32x4 c) {
  return __builtin_amdgcn_mfma_f32_16x16x32_bf16(a, b, c, 0, 0, 0);
}

__device__ __forceinline__ f32x4 MFMA16(half4 a, half4 b, f32x4 c) {
  return __builtin_amdgcn_mfma_f32_16x16x16f16(a, b, c, 0, 0, 0);
}

__device__ __forceinline__ unsigned short f2bf(float f) {
  unsigned u = __float_as_uint(f);
  u += 0x7fffu + ((u >> 16) & 1u);
  return (unsigned short)(u >> 16);
}

__device__ __forceinline__ unsigned long long pack4(float a, float b, float c, float d) {
  unsigned lo = (unsigned)f2bf(a) | ((unsigned)f2bf(b) << 16);
  unsigned hi = (unsigned)f2bf(c) | ((unsigned)f2bf(d) << 16);
  return (unsigned long long)lo | ((unsigned long long)hi << 32);
}

// ---- Prologue: PRE-SWIZZLED (per-lane fragment order) weight/rpe buffers.
//   qkv_wb: [(o*8+h)*2+m][ks][lane][8] bf16  (o=0 q-rows pre-scaled)
//   proj_wb:[h*2+m][ks][lane][8] bf16
//   rpe:    [(h*4+it)*4+jt][lane][4] f32
// 1155*256 = 295680 threads exact.
__global__ void prep_kernel(const float* __restrict__ qkv_w,
                            const float* __restrict__ proj_w,
                            const float* __restrict__ table,
                            const int* __restrict__ rel,
                            const float* __restrict__ qkv_b,
                            unsigned short* __restrict__ qkv_wb,
                            unsigned short* __restrict__ proj_wb,
                            float* __restrict__ rpe,
                            float* __restrict__ qkv_bs) {
  int idx = blockIdx.x * 256 + threadIdx.x;
  if (idx < 196608) {
    int e    = idx & 7;
    int lane = (idx >> 3) & 63;
    int ks   = (idx >> 9) & 7;
    int m    = (idx >> 12) & 1;
    int h    = (idx >> 13) & 7;
    int o    = idx >> 16;                    // 0=q 1=k 2=v
    int lr = lane & 15, lg = lane >> 4;
    int row = o * 256 + h * 32 + m * 16 + lr;
    int col = ks * 32 + lg * 8 + e;
    float v = qkv_w[row * 256 + col];
    if (o == 0) v *= SCALE;
    qkv_wb[idx] = f2bf(v);
  } else if (idx < 262144) {
    int p = idx - 196608;
    int e    = p & 7;
    int lane = (p >> 3) & 63;
    int ks   = (p >> 9) & 7;
    int m    = (p >> 12) & 1;
    int h    = (p >> 13) & 7;
    int lr = lane & 15, lg = lane >> 4;
    int row = h * 32 + m * 16 + lr;
    int col = ks * 32 + lg * 8 + e;
    proj_wb[p] = f2bf(proj_w[row * 256 + col]);
  } else if (idx < 294912) {
    int t = idx - 262144;                    // packed rpe
    int e    = t & 3;
    int lane = (t >> 2) & 63;
    int jt   = (t >> 8) & 3;
    int it   = (t >> 10) & 3;
    int h    = t >> 12;
    int lr = lane & 15, lg = lane >> 4;
    int i = it * 16 + lr;
    int j = jt * 16 + lg * 4 + e;
    rpe[t] = table[rel[i * 64 + j] * 8 + h];
  } else {
    int i = idx - 294912;                    // 0..767
    qkv_bs[i] = qkv_b[i] * (i < 256 ? SCALE : 1.0f);
  }
}

// ---- Main fused kernel: one block per window, 8 waves = 8 heads.
// R10: q/k GEMM split into two sequential passes so peak live regs fit the
// 128-reg budget of __launch_bounds__(512,4) -> 2 blocks/CU (4 waves/SIMD,
// 2x latency overlap). Spill diagnostic: WRITE_SIZE >> 267 MB means revert.
__global__ __launch_bounds__(512, 4)
void win_attn_kernel(const float* __restrict__ x,
                     const float* __restrict__ mask,
                     const unsigned short* __restrict__ qkv_wb,
                     const float* __restrict__ qkv_bs,
                     const unsigned short* __restrict__ proj_wb,
                     const float* __restrict__ proj_b,
                     const float* __restrict__ rpe,
                     float* __restrict__ out) {
  __shared__ __align__(16) unsigned char smem[51200];
  unsigned short* xb = (unsigned short*)smem;        // [64][264] bf16
  float*          mk = (float*)(smem + 33792);       // [64][68]  f32
  const int bid  = blockIdx.x;
  const int tid  = threadIdx.x;
  const int w    = tid >> 6;     // wave = head
  const int lane = tid & 63;
  const int lr   = lane & 15;
  const int lg   = lane >> 4;

  // ---- Phase 1: stage x -> LDS bf16; mask -> LDS f32 (all coalesced)
  {
    const f32x4* xg = (const f32x4*)(x + (size_t)bid * 16384);
#pragma unroll
    for (int i = 0; i < 8; ++i) {
      int vi = i * 512 + tid;                 // 4096 float4
      f32x4 v = xg[vi];
      int row = vi >> 6;
      int col = (vi & 63) * 4;
      *(unsigned long long*)&xb[row * 264 + col] = pack4(v[0], v[1], v[2], v[3]);
    }
    const f32x4* mg = (const f32x4*)(mask + (size_t)(bid & 1023) * 4096);
#pragma unroll
    for (int i = 0; i < 2; ++i) {
      int vi = i * 512 + tid;                 // 1024 float4
      f32x4 v = mg[vi];
      int row = vi >> 4;
      int col = (vi & 15) * 4;
      *(f32x4*)&mk[row * 68 + col] = v;
    }
  }
  __syncthreads();   // B0

  half4 qh[2][4], kh[2][4];    // [d-tile][tok-tile]

  // ---- Phase 2a: qT = Wq' @ xT  (bias in acc-init)
  {
    f32x4 qacc[2][4];
#pragma unroll
    for (int m = 0; m < 2; ++m) {
      f32x4 bq = *(const f32x4*)&qkv_bs[w * 32 + m * 16 + lg * 4];
#pragma unroll
      for (int t = 0; t < 4; ++t)
        qacc[m][t] = bq;
    }
    const unsigned short* wqp = qkv_wb + (size_t)((0 * 8 + w) * 2) * 4096 + lane * 8;
#pragma unroll
    for (int ks = 0; ks < 8; ++ks) {
      short8 xf[4];
#pragma unroll
      for (int t = 0; t < 4; ++t)
        xf[t] = *(const short8*)&xb[(t * 16 + lr) * 264 + ks * 32 + lg * 8];
      short8 wq[2];
#pragma unroll
      for (int m = 0; m < 2; ++m)
        wq[m] = *(const short8*)&wqp[(m * 8 + ks) * 512];
#pragma unroll
      for (int m = 0; m < 2; ++m)
#pragma unroll
        for (int t = 0; t < 4; ++t)
          qacc[m][t] = MFMA32(wq[m], xf[t], qacc[m][t]);
    }
#pragma unroll
    for (int m = 0; m < 2; ++m)
#pragma unroll
      for (int t = 0; t < 4; ++t)
#pragma unroll
        for (int e = 0; e < 4; ++e)
          qh[m][t][e] = (_Float16)qacc[m][t][e];
  }

  // ---- Phase 2b: kT = Wk @ xT  (separate pass: halves peak live registers)
  {
    f32x4 kacc[2][4];
#pragma unroll
    for (int m = 0; m < 2; ++m) {
      f32x4 bk = *(const f32x4*)&qkv_bs[256 + w * 32 + m * 16 + lg * 4];
#pragma unroll
      for (int t = 0; t < 4; ++t)
        kacc[m][t] = bk;
    }
    const unsigned short* wkp = qkv_wb + (size_t)((1 * 8 + w) * 2) * 4096 + lane * 8;
#pragma unroll
    for (int ks = 0; ks < 8; ++ks) {
      short8 xf[4];
#pragma unroll
      for (int t = 0; t < 4; ++t)
        xf[t] = *(const short8*)&xb[(t * 16 + lr) * 264 + ks * 32 + lg * 8];
      short8 wk[2];
#pragma unroll
      for (int m = 0; m < 2; ++m)
        wk[m] = *(const short8*)&wkp[(m * 8 + ks) * 512];
#pragma unroll
      for (int m = 0; m < 2; ++m)
#pragma unroll
        for (int t = 0; t < 4; ++t)
          kacc[m][t] = MFMA32(wk[m], xf[t], kacc[m][t]);
    }
#pragma unroll
    for (int m = 0; m < 2; ++m)
#pragma unroll
      for (int t = 0; t < 4; ++t)
#pragma unroll
        for (int e = 0; e < 4; ++e)
          kh[m][t][e] = (_Float16)kacc[m][t][e];
  }

  // ---- Phase 3: S^T = k @ q^T with C-init = rpe + mask; softmax -> P^T
  half4 pb[4][4];    // [jt = PV k-step][it]
  {
    const float* rpe_h = rpe + (size_t)w * 4096 + lane * 4;   // packed
#pragma unroll
    for (int it = 0; it < 4; ++it) {
      f32x4 binit[4];
#pragma unroll
      for (int jt = 0; jt < 4; ++jt)
        binit[jt] = *(const f32x4*)&rpe_h[(it * 4 + jt) * 256];
#pragma unroll
      for (int jt = 0; jt < 4; ++jt) {
        f32x4 mv = *(const f32x4*)&mk[(it * 16 + lr) * 68 + jt * 16 + lg * 4];
#pragma unroll
        for (int e = 0; e < 4; ++e) binit[jt][e] += mv[e];
      }
      f32x4 sacc[4];
#pragma unroll
      for (int jt = 0; jt < 4; ++jt) {
        sacc[jt] = MFMA16(kh[0][jt], qh[0][it], binit[jt]);
        sacc[jt] = MFMA16(kh[1][jt], qh[1][it], sacc[jt]);
      }
      float mx = -3.0e38f;
#pragma unroll
      for (int jt = 0; jt < 4; ++jt)
#pragma unroll
        for (int e = 0; e < 4; ++e)
          mx = fmaxf(mx, sacc[jt][e]);
      mx = fmaxf(mx, __shfl_xor(mx, 16, 64));
      mx = fmaxf(mx, __shfl_xor(mx, 32, 64));
      float sum = 0.f;
#pragma unroll
      for (int jt = 0; jt < 4; ++jt)
#pragma unroll
        for (int e = 0; e < 4; ++e) {
          sacc[jt][e] = __expf(sacc[jt][e] - mx);
          sum += sacc[jt][e];
        }
      sum += __shfl_xor(sum, 16, 64);
      sum += __shfl_xor(sum, 32, 64);
      float inv = 1.0f / sum;
#pragma unroll
      for (int jt = 0; jt < 4; ++jt)
#pragma unroll
        for (int e = 0; e < 4; ++e)
          pb[jt][it][e] = (_Float16)(sacc[jt][e] * inv);
    }
  }

  // ---- Phase 4: v = x @ Wv^T (C-output IS the V^T A-frag); bias in acc-init
  half4 vh[4][2];    // [tok-tile = PV k-step][d-tile]
  {
    f32x4 vacc[4][2];
#pragma unroll
    for (int n = 0; n < 2; ++n) {
      float bv = qkv_bs[512 + w * 32 + n * 16 + lr];
      f32x4 iv = {bv, bv, bv, bv};
#pragma unroll
      for (int t = 0; t < 4; ++t)
        vacc[t][n] = iv;
    }
    const unsigned short* wvp = qkv_wb + (size_t)((2 * 8 + w) * 2) * 4096 + lane * 8;
#pragma unroll
    for (int ks = 0; ks < 8; ++ks) {
      short8 xf[4];
#pragma unroll
      for (int t = 0; t < 4; ++t)
        xf[t] = *(const short8*)&xb[(t * 16 + lr) * 264 + ks * 32 + lg * 8];
      short8 wv[2];
#pragma unroll
      for (int n = 0; n < 2; ++n)
        wv[n] = *(const short8*)&wvp[(n * 8 + ks) * 512];
#pragma unroll
      for (int t = 0; t < 4; ++t)
#pragma unroll
        for (int n = 0; n < 2; ++n)
          vacc[t][n] = MFMA32(xf[t], wv[n], vacc[t][n]);
    }
#pragma unroll
    for (int t = 0; t < 4; ++t)
#pragma unroll
      for (int n = 0; n < 2; ++n)
#pragma unroll
        for (int e = 0; e < 4; ++e)
          vh[t][n][e] = (_Float16)vacc[t][n][e];
  }
  __syncthreads();   // B1: x-buf dead

  // ---- Phase 5: O^T = V^T @ P^T
  {
    f32x4 oacc[2][4];   // [dt][it]
    const f32x4 z4 = {0.f, 0.f, 0.f, 0.f};
#pragma unroll
    for (int dt = 0; dt < 2; ++dt)
#pragma unroll
      for (int it = 0; it < 4; ++it)
        oacc[dt][it] = z4;
#pragma unroll
    for (int kj = 0; kj < 4; ++kj)
#pragma unroll
      for (int dt = 0; dt < 2; ++dt)
#pragma unroll
        for (int it = 0; it < 4; ++it)
          oacc[dt][it] = MFMA16(vh[kj][dt], pb[kj][it], oacc[dt][it]);
#pragma unroll
    for (int dt = 0; dt < 2; ++dt)
#pragma unroll
      for (int it = 0; it < 4; ++it)
        *(unsigned long long*)&xb[(it * 16 + lr) * 264 + w * 32 + dt * 16 + lg * 4]
            = pack4(oacc[dt][it][0], oacc[dt][it][1], oacc[dt][it][2], oacc[dt][it][3]);
  }
  __syncthreads();   // B2: O_all complete

  // ---- Phase 6: out^T = proj_w @ O_all^T; bias in acc-init; float4 stores
  {
    f32x4 pacc[2][4];
#pragma unroll
    for (int m = 0; m < 2; ++m) {
      f32x4 bp = *(const f32x4*)&proj_b[w * 32 + m * 16 + lg * 4];
#pragma unroll
      for (int t = 0; t < 4; ++t)
        pacc[m][t] = bp;
    }
    const unsigned short* pwp = proj_wb + (size_t)(w * 2) * 4096 + lane * 8;
#pragma unroll
    for (int ks = 0; ks < 8; ++ks) {
      short8 of[4];
#pragma unroll
      for (int t = 0; t < 4; ++t)
        of[t] = *(const short8*)&xb[(t * 16 + lr) * 264 + ks * 32 + lg * 8];
      short8 pw[2];
#pragma unroll
      for (int m = 0; m < 2; ++m)
        pw[m] = *(const short8*)&pwp[(m * 8 + ks) * 512];
#pragma unroll
      for (int m = 0; m < 2; ++m)
#pragma unroll
        for (int t = 0; t < 4; ++t)
          pacc[m][t] = MFMA32(pw[m], of[t], pacc[m][t]);
    }
    float* og = out + (size_t)bid * 16384;
#pragma unroll
    for (int m = 0; m < 2; ++m)
#pragma unroll
      for (int t = 0; t < 4; ++t)
        *(f32x4*)&og[(t * 16 + lr) * 256 + w * 32 + m * 16 + lg * 4] = pacc[m][t];
  }
}

extern "C" void kernel_launch(void* const* d_in, const int* in_sizes, int n_in,
                              void* d_out, int out_size, void* d_ws, size_t ws_size,
                              hipStream_t stream) {
  (void)in_sizes; (void)n_in; (void)out_size; (void)ws_size;
  const float* x      = (const float*)d_in[0];
  const float* mask   = (const float*)d_in[1];
  const float* qkv_w  = (const float*)d_in[2];
  const float* qkv_b  = (const float*)d_in[3];
  const float* proj_w = (const float*)d_in[4];
  const float* proj_b = (const float*)d_in[5];
  const float* rpb    = (const float*)d_in[6];
  const int*   rel    = (const int*)d_in[7];

  unsigned short* qkv_wb  = (unsigned short*)d_ws;                       // 393216 B
  unsigned short* proj_wb = (unsigned short*)((char*)d_ws + 393216);     // 131072 B
  float*          rpe     = (float*)((char*)d_ws + 524288);              // 131072 B
  float*          qkv_bs  = (float*)((char*)d_ws + 655360);              // 3072 B
  float*          out     = (float*)d_out;

  prep_kernel<<<dim3(1155), dim3(256), 0, stream>>>(qkv_w, proj_w, rpb, rel, qkv_b,
                                                    qkv_wb, proj_wb, rpe, qkv_bs);
  win_attn_kernel<<<dim3(4096), dim3(512), 0, stream>>>(x, mask, qkv_wb, qkv_bs,
                                                        proj_wb, proj_b, rpe, out);
}

// Round 11
// 656.134 us; speedup vs baseline: 1.0056x; 1.0056x over previous
//
#include <hip/hip_runtime.h>

#define SCALE 0.17677669529663687f

typedef __attribute__((ext_vector_type(8))) short short8;
typedef __attribute__((ext_vector_type(4))) float f32x4;
typedef __attribute__((ext_vector_type(4))) _Float16 half4;

__device__ __forceinline__ f32x4 MFMA32(short8 a, short8 b, f32x4 c) {
  return __builtin_amdgcn_mfma_f32_16x16x32_bf16(a, b, c, 0, 0, 0);
}

__device__ __forceinline__ f32x4 MFMA16(half4 a, half4 b, f32x4 c) {
  return __builtin_amdgcn_mfma_f32_16x16x16f16(a, b, c, 0, 0, 0);
}

__device__ __forceinline__ unsigned short f2bf(float f) {
  unsigned u = __float_as_uint(f);
  u += 0x7fffu + ((u >> 16) & 1u);
  return (unsigned short)(u >> 16);
}

__device__ __forceinline__ unsigned long long pack4(float a, float b, float c, float d) {
  unsigned lo = (unsigned)f2bf(a) | ((unsigned)f2bf(b) << 16);
  unsigned hi = (unsigned)f2bf(c) | ((unsigned)f2bf(d) << 16);
  return (unsigned long long)lo | ((unsigned long long)hi << 32);
}

// ---- Prologue: PRE-SWIZZLED (per-lane fragment order) weight/rpe buffers.
//   qkv_wb: [(o*8+h)*2+m][ks][lane][8] bf16  (o=0 q-rows pre-scaled)
//   proj_wb:[cb][ks][lane][8] bf16   (cb = column-block of 16 = h*2+m)
//   rpe:    [(h*4+it)*4+jt][lane][4] f32
// 1155*256 = 295680 threads exact.
__global__ void prep_kernel(const float* __restrict__ qkv_w,
                            const float* __restrict__ proj_w,
                            const float* __restrict__ table,
                            const int* __restrict__ rel,
                            const float* __restrict__ qkv_b,
                            unsigned short* __restrict__ qkv_wb,
                            unsigned short* __restrict__ proj_wb,
                            float* __restrict__ rpe,
                            float* __restrict__ qkv_bs) {
  int idx = blockIdx.x * 256 + threadIdx.x;
  if (idx < 196608) {
    int e    = idx & 7;
    int lane = (idx >> 3) & 63;
    int ks   = (idx >> 9) & 7;
    int m    = (idx >> 12) & 1;
    int h    = (idx >> 13) & 7;
    int o    = idx >> 16;                    // 0=q 1=k 2=v
    int lr = lane & 15, lg = lane >> 4;
    int row = o * 256 + h * 32 + m * 16 + lr;
    int col = ks * 32 + lg * 8 + e;
    float v = qkv_w[row * 256 + col];
    if (o == 0) v *= SCALE;
    qkv_wb[idx] = f2bf(v);
  } else if (idx < 262144) {
    int p = idx - 196608;
    int e    = p & 7;
    int lane = (p >> 3) & 63;
    int ks   = (p >> 9) & 7;
    int m    = (p >> 12) & 1;
    int h    = (p >> 13) & 7;
    int lr = lane & 15, lg = lane >> 4;
    int row = h * 32 + m * 16 + lr;
    int col = ks * 32 + lg * 8 + e;
    proj_wb[p] = f2bf(proj_w[row * 256 + col]);
  } else if (idx < 294912) {
    int t = idx - 262144;                    // packed rpe
    int e    = t & 3;
    int lane = (t >> 2) & 63;
    int jt   = (t >> 8) & 3;
    int it   = (t >> 10) & 3;
    int h    = t >> 12;
    int lr = lane & 15, lg = lane >> 4;
    int i = it * 16 + lr;
    int j = jt * 16 + lg * 4 + e;
    rpe[t] = table[rel[i * 64 + j] * 8 + h];
  } else {
    int i = idx - 294912;                    // 0..767
    qkv_bs[i] = qkv_b[i] * (i < 256 ? SCALE : 1.0f);
  }
}

// ---- Main fused kernel: one block per window, 256 threads = 4 waves;
// each wave processes TWO heads sequentially (head-A's O kept packed in
// 16 VGPRs while head-B runs). 512-thread blocks quantized occupancy to
// 1 block/CU (R5-R10 all 23%); 256-thread blocks + reg cap 170 ((256,3))
// -> 3 blocks/CU, 3 waves/SIMD, cross-block phase mixing.
// Spill tripwire: WRITE_SIZE >> 267 MB.
__global__ __launch_bounds__(256, 3)
void win_attn_kernel(const float* __restrict__ x,
                     const float* __restrict__ mask,
                     const unsigned short* __restrict__ qkv_wb,
                     const float* __restrict__ qkv_bs,
                     const unsigned short* __restrict__ proj_wb,
                     const float* __restrict__ proj_b,
                     const float* __restrict__ rpe,
                     float* __restrict__ out) {
  __shared__ __align__(16) unsigned char smem[51200];
  unsigned short* xb = (unsigned short*)smem;        // [64][264] bf16
  float*          mk = (float*)(smem + 33792);       // [64][68]  f32
  const int bid  = blockIdx.x;
  const int tid  = threadIdx.x;
  const int w4   = tid >> 6;     // wave 0..3
  const int lane = tid & 63;
  const int lr   = lane & 15;
  const int lg   = lane >> 4;

  // ---- Phase 1: stage x -> LDS bf16; mask -> LDS f32 (all coalesced)
  {
    const f32x4* xg = (const f32x4*)(x + (size_t)bid * 16384);
#pragma unroll
    for (int i = 0; i < 16; ++i) {
      int vi = i * 256 + tid;                 // 4096 float4
      f32x4 v = xg[vi];
      int row = vi >> 6;
      int col = (vi & 63) * 4;
      *(unsigned long long*)&xb[row * 264 + col] = pack4(v[0], v[1], v[2], v[3]);
    }
    const f32x4* mg = (const f32x4*)(mask + (size_t)(bid & 1023) * 4096);
#pragma unroll
    for (int i = 0; i < 4; ++i) {
      int vi = i * 256 + tid;                 // 1024 float4
      f32x4 v = mg[vi];
      int row = vi >> 4;
      int col = (vi & 15) * 4;
      *(f32x4*)&mk[row * 68 + col] = v;
    }
  }
  __syncthreads();   // B0

  unsigned long long osave[2][2][4];   // [hh][dt][it] packed bf16x4

#pragma unroll
  for (int hh = 0; hh < 2; ++hh) {
    const int h = w4 * 2 + hh;

    // ---- Phase 2: qT = Wq' @ xT, kT = Wk @ xT  (bias pre-loaded into acc)
    half4 qh[2][4], kh[2][4];    // [d-tile][tok-tile]
    {
      f32x4 qacc[2][4], kacc[2][4];
#pragma unroll
      for (int m = 0; m < 2; ++m) {
        f32x4 bq = *(const f32x4*)&qkv_bs[h * 32 + m * 16 + lg * 4];
        f32x4 bk = *(const f32x4*)&qkv_bs[256 + h * 32 + m * 16 + lg * 4];
#pragma unroll
        for (int t = 0; t < 4; ++t) {
          qacc[m][t] = bq;
          kacc[m][t] = bk;
        }
      }
      const unsigned short* wqp = qkv_wb + (size_t)((0 * 8 + h) * 2) * 4096 + lane * 8;
      const unsigned short* wkp = qkv_wb + (size_t)((1 * 8 + h) * 2) * 4096 + lane * 8;
#pragma unroll
      for (int ks = 0; ks < 8; ++ks) {
        short8 xf[4];
#pragma unroll
        for (int t = 0; t < 4; ++t)
          xf[t] = *(const short8*)&xb[(t * 16 + lr) * 264 + ks * 32 + lg * 8];
        short8 wq[2], wk[2];
#pragma unroll
        for (int m = 0; m < 2; ++m) {
          wq[m] = *(const short8*)&wqp[(m * 8 + ks) * 512];
          wk[m] = *(const short8*)&wkp[(m * 8 + ks) * 512];
        }
#pragma unroll
        for (int m = 0; m < 2; ++m)
#pragma unroll
          for (int t = 0; t < 4; ++t) {
            qacc[m][t] = MFMA32(wq[m], xf[t], qacc[m][t]);
            kacc[m][t] = MFMA32(wk[m], xf[t], kacc[m][t]);
          }
      }
#pragma unroll
      for (int m = 0; m < 2; ++m)
#pragma unroll
        for (int t = 0; t < 4; ++t)
#pragma unroll
          for (int e = 0; e < 4; ++e) {
            qh[m][t][e] = (_Float16)qacc[m][t][e];
            kh[m][t][e] = (_Float16)kacc[m][t][e];
          }
    }

    // ---- Phase 3: S^T = k @ q^T with C-init = rpe + mask; softmax -> P^T
    half4 pb[4][4];    // [jt = PV k-step][it]
    {
      const float* rpe_h = rpe + (size_t)h * 4096 + lane * 4;   // packed
#pragma unroll
      for (int it = 0; it < 4; ++it) {
        f32x4 binit[4];
#pragma unroll
        for (int jt = 0; jt < 4; ++jt)
          binit[jt] = *(const f32x4*)&rpe_h[(it * 4 + jt) * 256];
#pragma unroll
        for (int jt = 0; jt < 4; ++jt) {
          f32x4 mv = *(const f32x4*)&mk[(it * 16 + lr) * 68 + jt * 16 + lg * 4];
#pragma unroll
          for (int e = 0; e < 4; ++e) binit[jt][e] += mv[e];
        }
        f32x4 sacc[4];
#pragma unroll
        for (int jt = 0; jt < 4; ++jt) {
          sacc[jt] = MFMA16(kh[0][jt], qh[0][it], binit[jt]);
          sacc[jt] = MFMA16(kh[1][jt], qh[1][it], sacc[jt]);
        }
        float mx = -3.0e38f;
#pragma unroll
        for (int jt = 0; jt < 4; ++jt)
#pragma unroll
          for (int e = 0; e < 4; ++e)
            mx = fmaxf(mx, sacc[jt][e]);
        mx = fmaxf(mx, __shfl_xor(mx, 16, 64));
        mx = fmaxf(mx, __shfl_xor(mx, 32, 64));
        float sum = 0.f;
#pragma unroll
        for (int jt = 0; jt < 4; ++jt)
#pragma unroll
          for (int e = 0; e < 4; ++e) {
            sacc[jt][e] = __expf(sacc[jt][e] - mx);
            sum += sacc[jt][e];
          }
        sum += __shfl_xor(sum, 16, 64);
        sum += __shfl_xor(sum, 32, 64);
        float inv = 1.0f / sum;
#pragma unroll
        for (int jt = 0; jt < 4; ++jt)
#pragma unroll
          for (int e = 0; e < 4; ++e)
            pb[jt][it][e] = (_Float16)(sacc[jt][e] * inv);
      }
    }

    // ---- Phase 4: v = x @ Wv^T (C-output IS the V^T A-frag); bias in init
    half4 vh[4][2];    // [tok-tile = PV k-step][d-tile]
    {
      f32x4 vacc[4][2];
#pragma unroll
      for (int n = 0; n < 2; ++n) {
        float bv = qkv_bs[512 + h * 32 + n * 16 + lr];
        f32x4 iv = {bv, bv, bv, bv};
#pragma unroll
        for (int t = 0; t < 4; ++t)
          vacc[t][n] = iv;
      }
      const unsigned short* wvp = qkv_wb + (size_t)((2 * 8 + h) * 2) * 4096 + lane * 8;
#pragma unroll
      for (int ks = 0; ks < 8; ++ks) {
        short8 xf[4];
#pragma unroll
        for (int t = 0; t < 4; ++t)
          xf[t] = *(const short8*)&xb[(t * 16 + lr) * 264 + ks * 32 + lg * 8];
        short8 wv[2];
#pragma unroll
        for (int n = 0; n < 2; ++n)
          wv[n] = *(const short8*)&wvp[(n * 8 + ks) * 512];
#pragma unroll
        for (int t = 0; t < 4; ++t)
#pragma unroll
          for (int n = 0; n < 2; ++n)
            vacc[t][n] = MFMA32(xf[t], wv[n], vacc[t][n]);
      }
#pragma unroll
      for (int t = 0; t < 4; ++t)
#pragma unroll
        for (int n = 0; n < 2; ++n)
#pragma unroll
          for (int e = 0; e < 4; ++e)
            vh[t][n][e] = (_Float16)vacc[t][n][e];
    }

    // ---- Phase 5: O^T = V^T @ P^T ; keep packed in registers
    {
      f32x4 oacc[2][4];   // [dt][it]
      const f32x4 z4 = {0.f, 0.f, 0.f, 0.f};
#pragma unroll
      for (int dt = 0; dt < 2; ++dt)
#pragma unroll
        for (int it = 0; it < 4; ++it)
          oacc[dt][it] = z4;
#pragma unroll
      for (int kj = 0; kj < 4; ++kj)
#pragma unroll
        for (int dt = 0; dt < 2; ++dt)
#pragma unroll
          for (int it = 0; it < 4; ++it)
            oacc[dt][it] = MFMA16(vh[kj][dt], pb[kj][it], oacc[dt][it]);
#pragma unroll
      for (int dt = 0; dt < 2; ++dt)
#pragma unroll
        for (int it = 0; it < 4; ++it)
          osave[hh][dt][it] = pack4(oacc[dt][it][0], oacc[dt][it][1],
                                    oacc[dt][it][2], oacc[dt][it][3]);
    }
  }
  __syncthreads();   // B1: all waves done reading xb — xb dead

  // write both heads' O into xb: row it*16+lr, col h*32 + dt*16 + lg*4
#pragma unroll
  for (int hh = 0; hh < 2; ++hh)
#pragma unroll
    for (int dt = 0; dt < 2; ++dt)
#pragma unroll
      for (int it = 0; it < 4; ++it)
        *(unsigned long long*)&xb[(it * 16 + lr) * 264 + (w4 * 2 + hh) * 32 + dt * 16 + lg * 4]
            = osave[hh][dt][it];
  __syncthreads();   // B2: O_all complete

  // ---- Phase 6: out^T = proj_w @ O_all^T; wave w4 owns 64 output cols
  {
    f32x4 pacc[4][4];   // [mm][t]
#pragma unroll
    for (int mm = 0; mm < 4; ++mm) {
      f32x4 bp = *(const f32x4*)&proj_b[w4 * 64 + mm * 16 + lg * 4];
#pragma unroll
      for (int t = 0; t < 4; ++t)
        pacc[mm][t] = bp;
    }
    const unsigned short* pwp = proj_wb + (size_t)(w4 * 4) * 4096 + lane * 8;
#pragma unroll
    for (int ks = 0; ks < 8; ++ks) {
      short8 of[4];
#pragma unroll
      for (int t = 0; t < 4; ++t)
        of[t] = *(const short8*)&xb[(t * 16 + lr) * 264 + ks * 32 + lg * 8];
      short8 pw[4];
#pragma unroll
      for (int mm = 0; mm < 4; ++mm)
        pw[mm] = *(const short8*)&pwp[mm * 4096 + ks * 512];
#pragma unroll
      for (int mm = 0; mm < 4; ++mm)
#pragma unroll
        for (int t = 0; t < 4; ++t)
          pacc[mm][t] = MFMA32(pw[mm], of[t], pacc[mm][t]);
    }
    float* og = out + (size_t)bid * 16384;
#pragma unroll
    for (int mm = 0; mm < 4; ++mm)
#pragma unroll
      for (int t = 0; t < 4; ++t)
        *(f32x4*)&og[(t * 16 + lr) * 256 + w4 * 64 + mm * 16 + lg * 4] = pacc[mm][t];
  }
}

extern "C" void kernel_launch(void* const* d_in, const int* in_sizes, int n_in,
                              void* d_out, int out_size, void* d_ws, size_t ws_size,
                              hipStream_t stream) {
  (void)in_sizes; (void)n_in; (void)out_size; (void)ws_size;
  const float* x      = (const float*)d_in[0];
  const float* mask   = (const float*)d_in[1];
  const float* qkv_w  = (const float*)d_in[2];
  const float* qkv_b  = (const float*)d_in[3];
  const float* proj_w = (const float*)d_in[4];
  const float* proj_b = (const float*)d_in[5];
  const float* rpb    = (const float*)d_in[6];
  const int*   rel    = (const int*)d_in[7];

  unsigned short* qkv_wb  = (unsigned short*)d_ws;                       // 393216 B
  unsigned short* proj_wb = (unsigned short*)((char*)d_ws + 393216);     // 131072 B
  float*          rpe     = (float*)((char*)d_ws + 524288);              // 131072 B
  float*          qkv_bs  = (float*)((char*)d_ws + 655360);              // 3072 B
  float*          out     = (float*)d_out;

  prep_kernel<<<dim3(1155), dim3(256), 0, stream>>>(qkv_w, proj_w, rpb, rel, qkv_b,
                                                    qkv_wb, proj_wb, rpe, qkv_bs);
  win_attn_kernel<<<dim3(4096), dim3(256), 0, stream>>>(x, mask, qkv_wb, qkv_bs,
                                                        proj_wb, proj_b, rpe, out);
}

// Round 12
// 332.862 us; speedup vs baseline: 1.9822x; 1.9712x over previous
//
#include <hip/hip_runtime.h>

#define SCALE 0.17677669529663687f

typedef __attribute__((ext_vector_type(8))) short short8;
typedef __attribute__((ext_vector_type(4))) float f32x4;
typedef __attribute__((ext_vector_type(4))) _Float16 half4;

__device__ __forceinline__ f32x4 MFMA32(short8 a, short8 b, f32x4 c) {
  return __builtin_amdgcn_mfma_f32_16x16x32_bf16(a, b, c, 0, 0, 0);
}

__device__ __forceinline__ f32x4 MFMA16(half4 a, half4 b, f32x4 c) {
  return __builtin_amdgcn_mfma_f32_16x16x16f16(a, b, c, 0, 0, 0);
}

__device__ __forceinline__ unsigned short f2bf(float f) {
  unsigned u = __float_as_uint(f);
  u += 0x7fffu + ((u >> 16) & 1u);
  return (unsigned short)(u >> 16);
}

__device__ __forceinline__ unsigned long long pack4(float a, float b, float c, float d) {
  unsigned lo = (unsigned)f2bf(a) | ((unsigned)f2bf(b) << 16);
  unsigned hi = (unsigned)f2bf(c) | ((unsigned)f2bf(d) << 16);
  return (unsigned long long)lo | ((unsigned long long)hi << 32);
}

// ---- Prologue: PRE-SWIZZLED (per-lane fragment order) weight/rpe buffers.
//   qkv_wb: [(o*8+h)*2+m][ks][lane][8] bf16  (o=0 q-rows pre-scaled)
//   proj_wb:[h*2+m][ks][lane][8] bf16
//   rpe:    [(h*4+it)*4+jt][lane][4] f32
// 1155*256 = 295680 threads exact.
__global__ void prep_kernel(const float* __restrict__ qkv_w,
                            const float* __restrict__ proj_w,
                            const float* __restrict__ table,
                            const int* __restrict__ rel,
                            const float* __restrict__ qkv_b,
                            unsigned short* __restrict__ qkv_wb,
                            unsigned short* __restrict__ proj_wb,
                            float* __restrict__ rpe,
                            float* __restrict__ qkv_bs) {
  int idx = blockIdx.x * 256 + threadIdx.x;
  if (idx < 196608) {
    int e    = idx & 7;
    int lane = (idx >> 3) & 63;
    int ks   = (idx >> 9) & 7;
    int m    = (idx >> 12) & 1;
    int h    = (idx >> 13) & 7;
    int o    = idx >> 16;                    // 0=q 1=k 2=v
    int lr = lane & 15, lg = lane >> 4;
    int row = o * 256 + h * 32 + m * 16 + lr;
    int col = ks * 32 + lg * 8 + e;
    float v = qkv_w[row * 256 + col];
    if (o == 0) v *= SCALE;
    qkv_wb[idx] = f2bf(v);
  } else if (idx < 262144) {
    int p = idx - 196608;
    int e    = p & 7;
    int lane = (p >> 3) & 63;
    int ks   = (p >> 9) & 7;
    int m    = (p >> 12) & 1;
    int h    = (p >> 13) & 7;
    int lr = lane & 15, lg = lane >> 4;
    int row = h * 32 + m * 16 + lr;
    int col = ks * 32 + lg * 8 + e;
    proj_wb[p] = f2bf(proj_w[row * 256 + col]);
  } else if (idx < 294912) {
    int t = idx - 262144;                    // packed rpe
    int e    = t & 3;
    int lane = (t >> 2) & 63;
    int jt   = (t >> 8) & 3;
    int it   = (t >> 10) & 3;
    int h    = t >> 12;
    int lr = lane & 15, lg = lane >> 4;
    int i = it * 16 + lr;
    int j = jt * 16 + lg * 4 + e;
    rpe[t] = table[rel[i * 64 + j] * 8 + h];
  } else {
    int i = idx - 294912;                    // 0..767
    qkv_bs[i] = qkv_b[i] * (i < 256 ? SCALE : 1.0f);
  }
}

// ---- Main fused kernel: one block per window, 8 waves = 8 heads.
// R12 = R9 + MANUAL 1-deep software pipelining: next-iteration xf/weight/rpe
// loads issued before the current MFMA chain (the compiler wasn't doing it —
// VGPR_Count 108 of 256 budget; ~148 idle regs now fund prefetch).
// Natural regs (~512,2): 3 failed attempts (R3/R10/R11) prove caps spill.
__global__ __launch_bounds__(512, 2)
void win_attn_kernel(const float* __restrict__ x,
                     const float* __restrict__ mask,
                     const unsigned short* __restrict__ qkv_wb,
                     const float* __restrict__ qkv_bs,
                     const unsigned short* __restrict__ proj_wb,
                     const float* __restrict__ proj_b,
                     const float* __restrict__ rpe,
                     float* __restrict__ out) {
  __shared__ __align__(16) unsigned char smem[51200];
  unsigned short* xb = (unsigned short*)smem;        // [64][264] bf16
  float*          mk = (float*)(smem + 33792);       // [64][68]  f32
  const int bid  = blockIdx.x;
  const int tid  = threadIdx.x;
  const int w    = tid >> 6;     // wave = head
  const int lane = tid & 63;
  const int lr   = lane & 15;
  const int lg   = lane >> 4;

  // ---- Phase 1: ALL global loads issued first (10 in flight), then pack
  {
    const f32x4* xg = (const f32x4*)(x + (size_t)bid * 16384);
    const f32x4* mg = (const f32x4*)(mask + (size_t)(bid & 1023) * 4096);
    f32x4 rx[8], rm[2];
#pragma unroll
    for (int i = 0; i < 8; ++i)
      rx[i] = xg[i * 512 + tid];
#pragma unroll
    for (int i = 0; i < 2; ++i)
      rm[i] = mg[i * 512 + tid];
#pragma unroll
    for (int i = 0; i < 8; ++i) {
      int vi = i * 512 + tid;
      *(unsigned long long*)&xb[(vi >> 6) * 264 + (vi & 63) * 4]
          = pack4(rx[i][0], rx[i][1], rx[i][2], rx[i][3]);
    }
#pragma unroll
    for (int i = 0; i < 2; ++i) {
      int vi = i * 512 + tid;
      *(f32x4*)&mk[(vi >> 4) * 68 + (vi & 15) * 4] = rm[i];
    }
  }
  __syncthreads();   // B0

  // ---- Phase 2: qT = Wq' @ xT, kT = Wk @ xT  (1-deep SWP prefetch)
  half4 qh[2][4], kh[2][4];    // [d-tile][tok-tile]
  {
    f32x4 qacc[2][4], kacc[2][4];
#pragma unroll
    for (int m = 0; m < 2; ++m) {
      f32x4 bq = *(const f32x4*)&qkv_bs[w * 32 + m * 16 + lg * 4];
      f32x4 bk = *(const f32x4*)&qkv_bs[256 + w * 32 + m * 16 + lg * 4];
#pragma unroll
      for (int t = 0; t < 4; ++t) {
        qacc[m][t] = bq;
        kacc[m][t] = bk;
      }
    }
    const unsigned short* wqp = qkv_wb + (size_t)((0 * 8 + w) * 2) * 4096 + lane * 8;
    const unsigned short* wkp = qkv_wb + (size_t)((1 * 8 + w) * 2) * 4096 + lane * 8;
    short8 xf[4], wq[2], wk[2];
#pragma unroll
    for (int t = 0; t < 4; ++t)
      xf[t] = *(const short8*)&xb[(t * 16 + lr) * 264 + lg * 8];
#pragma unroll
    for (int m = 0; m < 2; ++m) {
      wq[m] = *(const short8*)&wqp[(m * 8) * 512];
      wk[m] = *(const short8*)&wkp[(m * 8) * 512];
    }
#pragma unroll
    for (int ks = 0; ks < 8; ++ks) {
      short8 xfn[4], wqn[2], wkn[2];
      if (ks < 7) {
#pragma unroll
        for (int t = 0; t < 4; ++t)
          xfn[t] = *(const short8*)&xb[(t * 16 + lr) * 264 + (ks + 1) * 32 + lg * 8];
#pragma unroll
        for (int m = 0; m < 2; ++m) {
          wqn[m] = *(const short8*)&wqp[(m * 8 + ks + 1) * 512];
          wkn[m] = *(const short8*)&wkp[(m * 8 + ks + 1) * 512];
        }
      }
#pragma unroll
      for (int m = 0; m < 2; ++m)
#pragma unroll
        for (int t = 0; t < 4; ++t) {
          qacc[m][t] = MFMA32(wq[m], xf[t], qacc[m][t]);
          kacc[m][t] = MFMA32(wk[m], xf[t], kacc[m][t]);
        }
      if (ks < 7) {
#pragma unroll
        for (int t = 0; t < 4; ++t) xf[t] = xfn[t];
#pragma unroll
        for (int m = 0; m < 2; ++m) { wq[m] = wqn[m]; wk[m] = wkn[m]; }
      }
    }
#pragma unroll
    for (int m = 0; m < 2; ++m)
#pragma unroll
      for (int t = 0; t < 4; ++t)
#pragma unroll
        for (int e = 0; e < 4; ++e) {
          qh[m][t][e] = (_Float16)qacc[m][t][e];
          kh[m][t][e] = (_Float16)kacc[m][t][e];
        }
  }

  // ---- Phase 3: S^T = k @ q^T with C-init = rpe + mask; softmax -> P^T
  // rpe prefetched one it ahead; mask from LDS (cheap).
  half4 pb[4][4];    // [jt = PV k-step][it]
  {
    const float* rpe_h = rpe + (size_t)w * 4096 + lane * 4;   // packed
    f32x4 rp[4];
#pragma unroll
    for (int jt = 0; jt < 4; ++jt)
      rp[jt] = *(const f32x4*)&rpe_h[jt * 256];
#pragma unroll
    for (int it = 0; it < 4; ++it) {
      f32x4 rpn[4];
      if (it < 3) {
#pragma unroll
        for (int jt = 0; jt < 4; ++jt)
          rpn[jt] = *(const f32x4*)&rpe_h[((it + 1) * 4 + jt) * 256];
      }
      f32x4 binit[4];
#pragma unroll
      for (int jt = 0; jt < 4; ++jt) {
        f32x4 mv = *(const f32x4*)&mk[(it * 16 + lr) * 68 + jt * 16 + lg * 4];
#pragma unroll
        for (int e = 0; e < 4; ++e) binit[jt][e] = rp[jt][e] + mv[e];
      }
      f32x4 sacc[4];
#pragma unroll
      for (int jt = 0; jt < 4; ++jt) {
        sacc[jt] = MFMA16(kh[0][jt], qh[0][it], binit[jt]);
        sacc[jt] = MFMA16(kh[1][jt], qh[1][it], sacc[jt]);
      }
      float mx = -3.0e38f;
#pragma unroll
      for (int jt = 0; jt < 4; ++jt)
#pragma unroll
        for (int e = 0; e < 4; ++e)
          mx = fmaxf(mx, sacc[jt][e]);
      mx = fmaxf(mx, __shfl_xor(mx, 16, 64));
      mx = fmaxf(mx, __shfl_xor(mx, 32, 64));
      float sum = 0.f;
#pragma unroll
      for (int jt = 0; jt < 4; ++jt)
#pragma unroll
        for (int e = 0; e < 4; ++e) {
          sacc[jt][e] = __expf(sacc[jt][e] - mx);
          sum += sacc[jt][e];
        }
      sum += __shfl_xor(sum, 16, 64);
      sum += __shfl_xor(sum, 32, 64);
      float inv = 1.0f / sum;
#pragma unroll
      for (int jt = 0; jt < 4; ++jt)
#pragma unroll
        for (int e = 0; e < 4; ++e)
          pb[jt][it][e] = (_Float16)(sacc[jt][e] * inv);
      if (it < 3) {
#pragma unroll
        for (int jt = 0; jt < 4; ++jt) rp[jt] = rpn[jt];
      }
    }
  }

  // ---- Phase 4: v = x @ Wv^T (1-deep SWP prefetch); bias in acc-init
  half4 vh[4][2];    // [tok-tile = PV k-step][d-tile]
  {
    f32x4 vacc[4][2];
#pragma unroll
    for (int n = 0; n < 2; ++n) {
      float bv = qkv_bs[512 + w * 32 + n * 16 + lr];
      f32x4 iv = {bv, bv, bv, bv};
#pragma unroll
      for (int t = 0; t < 4; ++t)
        vacc[t][n] = iv;
    }
    const unsigned short* wvp = qkv_wb + (size_t)((2 * 8 + w) * 2) * 4096 + lane * 8;
    short8 xf[4], wv[2];
#pragma unroll
    for (int t = 0; t < 4; ++t)
      xf[t] = *(const short8*)&xb[(t * 16 + lr) * 264 + lg * 8];
#pragma unroll
    for (int n = 0; n < 2; ++n)
      wv[n] = *(const short8*)&wvp[(n * 8) * 512];
#pragma unroll
    for (int ks = 0; ks < 8; ++ks) {
      short8 xfn[4], wvn[2];
      if (ks < 7) {
#pragma unroll
        for (int t = 0; t < 4; ++t)
          xfn[t] = *(const short8*)&xb[(t * 16 + lr) * 264 + (ks + 1) * 32 + lg * 8];
#pragma unroll
        for (int n = 0; n < 2; ++n)
          wvn[n] = *(const short8*)&wvp[(n * 8 + ks + 1) * 512];
      }
#pragma unroll
      for (int t = 0; t < 4; ++t)
#pragma unroll
        for (int n = 0; n < 2; ++n)
          vacc[t][n] = MFMA32(xf[t], wv[n], vacc[t][n]);
      if (ks < 7) {
#pragma unroll
        for (int t = 0; t < 4; ++t) xf[t] = xfn[t];
#pragma unroll
        for (int n = 0; n < 2; ++n) wv[n] = wvn[n];
      }
    }
#pragma unroll
    for (int t = 0; t < 4; ++t)
#pragma unroll
      for (int n = 0; n < 2; ++n)
#pragma unroll
        for (int e = 0; e < 4; ++e)
          vh[t][n][e] = (_Float16)vacc[t][n][e];
  }
  __syncthreads();   // B1: x-buf dead

  // ---- Phase 5: O^T = V^T @ P^T
  {
    f32x4 oacc[2][4];   // [dt][it]
    const f32x4 z4 = {0.f, 0.f, 0.f, 0.f};
#pragma unroll
    for (int dt = 0; dt < 2; ++dt)
#pragma unroll
      for (int it = 0; it < 4; ++it)
        oacc[dt][it] = z4;
#pragma unroll
    for (int kj = 0; kj < 4; ++kj)
#pragma unroll
      for (int dt = 0; dt < 2; ++dt)
#pragma unroll
        for (int it = 0; it < 4; ++it)
          oacc[dt][it] = MFMA16(vh[kj][dt], pb[kj][it], oacc[dt][it]);
#pragma unroll
    for (int dt = 0; dt < 2; ++dt)
#pragma unroll
      for (int it = 0; it < 4; ++it)
        *(unsigned long long*)&xb[(it * 16 + lr) * 264 + w * 32 + dt * 16 + lg * 4]
            = pack4(oacc[dt][it][0], oacc[dt][it][1], oacc[dt][it][2], oacc[dt][it][3]);
  }
  __syncthreads();   // B2: O_all complete

  // ---- Phase 6: out^T = proj_w @ O_all^T (1-deep SWP prefetch)
  {
    f32x4 pacc[2][4];
#pragma unroll
    for (int m = 0; m < 2; ++m) {
      f32x4 bp = *(const f32x4*)&proj_b[w * 32 + m * 16 + lg * 4];
#pragma unroll
      for (int t = 0; t < 4; ++t)
        pacc[m][t] = bp;
    }
    const unsigned short* pwp = proj_wb + (size_t)(w * 2) * 4096 + lane * 8;
    short8 of[4], pw[2];
#pragma unroll
    for (int t = 0; t < 4; ++t)
      of[t] = *(const short8*)&xb[(t * 16 + lr) * 264 + lg * 8];
#pragma unroll
    for (int m = 0; m < 2; ++m)
      pw[m] = *(const short8*)&pwp[(m * 8) * 512];
#pragma unroll
    for (int ks = 0; ks < 8; ++ks) {
      short8 ofn[4], pwn[2];
      if (ks < 7) {
#pragma unroll
        for (int t = 0; t < 4; ++t)
          ofn[t] = *(const short8*)&xb[(t * 16 + lr) * 264 + (ks + 1) * 32 + lg * 8];
#pragma unroll
        for (int m = 0; m < 2; ++m)
          pwn[m] = *(const short8*)&pwp[(m * 8 + ks + 1) * 512];
      }
#pragma unroll
      for (int m = 0; m < 2; ++m)
#pragma unroll
        for (int t = 0; t < 4; ++t)
          pacc[m][t] = MFMA32(pw[m], of[t], pacc[m][t]);
      if (ks < 7) {
#pragma unroll
        for (int t = 0; t < 4; ++t) of[t] = ofn[t];
#pragma unroll
        for (int m = 0; m < 2; ++m) pw[m] = pwn[m];
      }
    }
    float* og = out + (size_t)bid * 16384;
#pragma unroll
    for (int m = 0; m < 2; ++m)
#pragma unroll
      for (int t = 0; t < 4; ++t)
        *(f32x4*)&og[(t * 16 + lr) * 256 + w * 32 + m * 16 + lg * 4] = pacc[m][t];
  }
}

extern "C" void kernel_launch(void* const* d_in, const int* in_sizes, int n_in,
                              void* d_out, int out_size, void* d_ws, size_t ws_size,
                              hipStream_t stream) {
  (void)in_sizes; (void)n_in; (void)out_size; (void)ws_size;
  const float* x      = (const float*)d_in[0];
  const float* mask   = (const float*)d_in[1];
  const float* qkv_w  = (const float*)d_in[2];
  const float* qkv_b  = (const float*)d_in[3];
  const float* proj_w = (const float*)d_in[4];
  const float* proj_b = (const float*)d_in[5];
  const float* rpb    = (const float*)d_in[6];
  const int*   rel    = (const int*)d_in[7];

  unsigned short* qkv_wb  = (unsigned short*)d_ws;                       // 393216 B
  unsigned short* proj_wb = (unsigned short*)((char*)d_ws + 393216);     // 131072 B
  float*          rpe     = (float*)((char*)d_ws + 524288);              // 131072 B
  float*          qkv_bs  = (float*)((char*)d_ws + 655360);              // 3072 B
  float*          out     = (float*)d_out;

  prep_kernel<<<dim3(1155), dim3(256), 0, stream>>>(qkv_w, proj_w, rpb, rel, qkv_b,
                                                    qkv_wb, proj_wb, rpe, qkv_bs);
  win_attn_kernel<<<dim3(4096), dim3(512), 0, stream>>>(x, mask, qkv_wb, qkv_bs,
                                                        proj_wb, proj_b, rpe, out);
}

// Round 13
// 319.443 us; speedup vs baseline: 2.0654x; 1.0420x over previous
//
#include <hip/hip_runtime.h>

#define SCALE 0.17677669529663687f

typedef __attribute__((ext_vector_type(8))) short short8;
typedef __attribute__((ext_vector_type(4))) float f32x4;
typedef __attribute__((ext_vector_type(4))) _Float16 half4;

__device__ __forceinline__ f32x4 MFMA32(short8 a, short8 b, f32x4 c) {
  return __builtin_amdgcn_mfma_f32_16x16x32_bf16(a, b, c, 0, 0, 0);
}

__device__ __forceinline__ f32x4 MFMA16(half4 a, half4 b, f32x4 c) {
  return __builtin_amdgcn_mfma_f32_16x16x16f16(a, b, c, 0, 0, 0);
}

__device__ __forceinline__ unsigned short f2bf(float f) {
  unsigned u = __float_as_uint(f);
  u += 0x7fffu + ((u >> 16) & 1u);
  return (unsigned short)(u >> 16);
}

__device__ __forceinline__ unsigned long long pack4(float a, float b, float c, float d) {
  unsigned lo = (unsigned)f2bf(a) | ((unsigned)f2bf(b) << 16);
  unsigned hi = (unsigned)f2bf(c) | ((unsigned)f2bf(d) << 16);
  return (unsigned long long)lo | ((unsigned long long)hi << 32);
}

// ---- Prologue: PRE-SWIZZLED (per-lane fragment order) weight/rpe buffers.
//   qkv_wb: [(o*8+h)*2+m][ks][lane][8] bf16  (o=0 q-rows pre-scaled)
//   proj_wb:[h*2+m][ks][lane][8] bf16
//   rpe:    [(h*4+it)*4+jt][lane][4] f32
// 1155*256 = 295680 threads exact.
__global__ void prep_kernel(const float* __restrict__ qkv_w,
                            const float* __restrict__ proj_w,
                            const float* __restrict__ table,
                            const int* __restrict__ rel,
                            const float* __restrict__ qkv_b,
                            unsigned short* __restrict__ qkv_wb,
                            unsigned short* __restrict__ proj_wb,
                            float* __restrict__ rpe,
                            float* __restrict__ qkv_bs) {
  int idx = blockIdx.x * 256 + threadIdx.x;
  if (idx < 196608) {
    int e    = idx & 7;
    int lane = (idx >> 3) & 63;
    int ks   = (idx >> 9) & 7;
    int m    = (idx >> 12) & 1;
    int h    = (idx >> 13) & 7;
    int o    = idx >> 16;                    // 0=q 1=k 2=v
    int lr = lane & 15, lg = lane >> 4;
    int row = o * 256 + h * 32 + m * 16 + lr;
    int col = ks * 32 + lg * 8 + e;
    float v = qkv_w[row * 256 + col];
    if (o == 0) v *= SCALE;
    qkv_wb[idx] = f2bf(v);
  } else if (idx < 262144) {
    int p = idx - 196608;
    int e    = p & 7;
    int lane = (p >> 3) & 63;
    int ks   = (p >> 9) & 7;
    int m    = (p >> 12) & 1;
    int h    = (p >> 13) & 7;
    int lr = lane & 15, lg = lane >> 4;
    int row = h * 32 + m * 16 + lr;
    int col = ks * 32 + lg * 8 + e;
    proj_wb[p] = f2bf(proj_w[row * 256 + col]);
  } else if (idx < 294912) {
    int t = idx - 262144;                    // packed rpe
    int e    = t & 3;
    int lane = (t >> 2) & 63;
    int jt   = (t >> 8) & 3;
    int it   = (t >> 10) & 3;
    int h    = t >> 12;
    int lr = lane & 15, lg = lane >> 4;
    int i = it * 16 + lr;
    int j = jt * 16 + lg * 4 + e;
    rpe[t] = table[rel[i * 64 + j] * 8 + h];
  } else {
    int i = idx - 294912;                    // 0..767
    qkv_bs[i] = qkv_b[i] * (i < 256 ? SCALE : 1.0f);
  }
}

// ---- Main fused kernel: one block per window, 8 waves = 8 heads.
// R13 = R9 + q/k/v GEMM merged into ONE xf pass (retry of R7 now that
// weights are pre-swizzled: merged loop issues 24-line bursts/ks, not the
// 96-line scatters that killed R7). PV starts right after softmax.
// Natural regs at (512,2); caps spill (R3/R10/R11). Spill tripwire: WRITE.
__global__ __launch_bounds__(512, 2)
void win_attn_kernel(const float* __restrict__ x,
                     const float* __restrict__ mask,
                     const unsigned short* __restrict__ qkv_wb,
                     const float* __restrict__ qkv_bs,
                     const unsigned short* __restrict__ proj_wb,
                     const float* __restrict__ proj_b,
                     const float* __restrict__ rpe,
                     float* __restrict__ out) {
  __shared__ __align__(16) unsigned char smem[51200];
  unsigned short* xb = (unsigned short*)smem;        // [64][264] bf16
  float*          mk = (float*)(smem + 33792);       // [64][68]  f32
  const int bid  = blockIdx.x;
  const int tid  = threadIdx.x;
  const int w    = tid >> 6;     // wave = head
  const int lane = tid & 63;
  const int lr   = lane & 15;
  const int lg   = lane >> 4;

  // ---- Phase 1: stage x -> LDS bf16; mask -> LDS f32 (all coalesced)
  {
    const f32x4* xg = (const f32x4*)(x + (size_t)bid * 16384);
    const f32x4* mg = (const f32x4*)(mask + (size_t)(bid & 1023) * 4096);
    f32x4 rx[8], rm[2];
#pragma unroll
    for (int i = 0; i < 8; ++i)
      rx[i] = xg[i * 512 + tid];
#pragma unroll
    for (int i = 0; i < 2; ++i)
      rm[i] = mg[i * 512 + tid];
#pragma unroll
    for (int i = 0; i < 8; ++i) {
      int vi = i * 512 + tid;
      *(unsigned long long*)&xb[(vi >> 6) * 264 + (vi & 63) * 4]
          = pack4(rx[i][0], rx[i][1], rx[i][2], rx[i][3]);
    }
#pragma unroll
    for (int i = 0; i < 2; ++i) {
      int vi = i * 512 + tid;
      *(f32x4*)&mk[(vi >> 4) * 68 + (vi & 15) * 4] = rm[i];
    }
  }
  __syncthreads();   // B0

  // ---- Phase 2 (merged): qT, kT, v in ONE xf pass — 24 MFMA per ks.
  // q/k C-output: lane holds [d = m*16+lg*4+e][tok = t*16+lr]  (MFMA16 frags)
  // v  C-output: lane holds [tok = t*16+lg*4+e][d = n*16+lr]   (V^T A-frag)
  half4 qh[2][4], kh[2][4];    // [d-tile][tok-tile]
  half4 vh[4][2];              // [tok-tile = PV k-step][d-tile]
  {
    f32x4 qacc[2][4], kacc[2][4], vacc[4][2];
#pragma unroll
    for (int m = 0; m < 2; ++m) {
      f32x4 bq = *(const f32x4*)&qkv_bs[w * 32 + m * 16 + lg * 4];
      f32x4 bk = *(const f32x4*)&qkv_bs[256 + w * 32 + m * 16 + lg * 4];
#pragma unroll
      for (int t = 0; t < 4; ++t) {
        qacc[m][t] = bq;
        kacc[m][t] = bk;
      }
    }
#pragma unroll
    for (int n = 0; n < 2; ++n) {
      float bv = qkv_bs[512 + w * 32 + n * 16 + lr];
      f32x4 iv = {bv, bv, bv, bv};
#pragma unroll
      for (int t = 0; t < 4; ++t)
        vacc[t][n] = iv;
    }
    const unsigned short* wqp = qkv_wb + (size_t)((0 * 8 + w) * 2) * 4096 + lane * 8;
    const unsigned short* wkp = qkv_wb + (size_t)((1 * 8 + w) * 2) * 4096 + lane * 8;
    const unsigned short* wvp = qkv_wb + (size_t)((2 * 8 + w) * 2) * 4096 + lane * 8;
#pragma unroll
    for (int ks = 0; ks < 8; ++ks) {
      short8 xf[4];
#pragma unroll
      for (int t = 0; t < 4; ++t)
        xf[t] = *(const short8*)&xb[(t * 16 + lr) * 264 + ks * 32 + lg * 8];
      short8 wq[2], wk[2], wv[2];
#pragma unroll
      for (int m = 0; m < 2; ++m) {
        wq[m] = *(const short8*)&wqp[(m * 8 + ks) * 512];
        wk[m] = *(const short8*)&wkp[(m * 8 + ks) * 512];
        wv[m] = *(const short8*)&wvp[(m * 8 + ks) * 512];
      }
#pragma unroll
      for (int m = 0; m < 2; ++m)
#pragma unroll
        for (int t = 0; t < 4; ++t) {
          qacc[m][t] = MFMA32(wq[m], xf[t], qacc[m][t]);
          kacc[m][t] = MFMA32(wk[m], xf[t], kacc[m][t]);
          vacc[t][m] = MFMA32(xf[t], wv[m], vacc[t][m]);
        }
    }
#pragma unroll
    for (int m = 0; m < 2; ++m)
#pragma unroll
      for (int t = 0; t < 4; ++t)
#pragma unroll
        for (int e = 0; e < 4; ++e) {
          qh[m][t][e] = (_Float16)qacc[m][t][e];
          kh[m][t][e] = (_Float16)kacc[m][t][e];
          vh[t][m][e] = (_Float16)vacc[t][m][e];
        }
  }
  __syncthreads();   // B1: all waves done reading xb — xb dead

  // ---- Phase 3: S^T = k @ q^T with C-init = rpe + mask; softmax -> P^T
  half4 pb[4][4];    // [jt = PV k-step][it]
  {
    const float* rpe_h = rpe + (size_t)w * 4096 + lane * 4;   // packed
#pragma unroll
    for (int it = 0; it < 4; ++it) {
      f32x4 binit[4];
#pragma unroll
      for (int jt = 0; jt < 4; ++jt)
        binit[jt] = *(const f32x4*)&rpe_h[(it * 4 + jt) * 256];
#pragma unroll
      for (int jt = 0; jt < 4; ++jt) {
        f32x4 mv = *(const f32x4*)&mk[(it * 16 + lr) * 68 + jt * 16 + lg * 4];
#pragma unroll
        for (int e = 0; e < 4; ++e) binit[jt][e] += mv[e];
      }
      f32x4 sacc[4];
#pragma unroll
      for (int jt = 0; jt < 4; ++jt) {
        sacc[jt] = MFMA16(kh[0][jt], qh[0][it], binit[jt]);
        sacc[jt] = MFMA16(kh[1][jt], qh[1][it], sacc[jt]);
      }
      float mx = -3.0e38f;
#pragma unroll
      for (int jt = 0; jt < 4; ++jt)
#pragma unroll
        for (int e = 0; e < 4; ++e)
          mx = fmaxf(mx, sacc[jt][e]);
      mx = fmaxf(mx, __shfl_xor(mx, 16, 64));
      mx = fmaxf(mx, __shfl_xor(mx, 32, 64));
      float sum = 0.f;
#pragma unroll
      for (int jt = 0; jt < 4; ++jt)
#pragma unroll
        for (int e = 0; e < 4; ++e) {
          sacc[jt][e] = __expf(sacc[jt][e] - mx);
          sum += sacc[jt][e];
        }
      sum += __shfl_xor(sum, 16, 64);
      sum += __shfl_xor(sum, 32, 64);
      float inv = 1.0f / sum;
#pragma unroll
      for (int jt = 0; jt < 4; ++jt)
#pragma unroll
        for (int e = 0; e < 4; ++e)
          pb[jt][it][e] = (_Float16)(sacc[jt][e] * inv);
    }
  }

  // ---- Phase 4: O^T = V^T @ P^T (immediately after softmax) ; O -> xb
  {
    f32x4 oacc[2][4];   // [dt][it]
    const f32x4 z4 = {0.f, 0.f, 0.f, 0.f};
#pragma unroll
    for (int dt = 0; dt < 2; ++dt)
#pragma unroll
      for (int it = 0; it < 4; ++it)
        oacc[dt][it] = z4;
#pragma unroll
    for (int kj = 0; kj < 4; ++kj)
#pragma unroll
      for (int dt = 0; dt < 2; ++dt)
#pragma unroll
        for (int it = 0; it < 4; ++it)
          oacc[dt][it] = MFMA16(vh[kj][dt], pb[kj][it], oacc[dt][it]);
#pragma unroll
    for (int dt = 0; dt < 2; ++dt)
#pragma unroll
      for (int it = 0; it < 4; ++it)
        *(unsigned long long*)&xb[(it * 16 + lr) * 264 + w * 32 + dt * 16 + lg * 4]
            = pack4(oacc[dt][it][0], oacc[dt][it][1], oacc[dt][it][2], oacc[dt][it][3]);
  }
  __syncthreads();   // B2: O_all complete

  // ---- Phase 5: out^T = proj_w @ O_all^T; bias in acc-init; float4 stores
  {
    f32x4 pacc[2][4];
#pragma unroll
    for (int m = 0; m < 2; ++m) {
      f32x4 bp = *(const f32x4*)&proj_b[w * 32 + m * 16 + lg * 4];
#pragma unroll
      for (int t = 0; t < 4; ++t)
        pacc[m][t] = bp;
    }
    const unsigned short* pwp = proj_wb + (size_t)(w * 2) * 4096 + lane * 8;
#pragma unroll
    for (int ks = 0; ks < 8; ++ks) {
      short8 of[4];
#pragma unroll
      for (int t = 0; t < 4; ++t)
        of[t] = *(const short8*)&xb[(t * 16 + lr) * 264 + ks * 32 + lg * 8];
      short8 pw[2];
#pragma unroll
      for (int m = 0; m < 2; ++m)
        pw[m] = *(const short8*)&pwp[(m * 8 + ks) * 512];
#pragma unroll
      for (int m = 0; m < 2; ++m)
#pragma unroll
        for (int t = 0; t < 4; ++t)
          pacc[m][t] = MFMA32(pw[m], of[t], pacc[m][t]);
    }
    float* og = out + (size_t)bid * 16384;
#pragma unroll
    for (int m = 0; m < 2; ++m)
#pragma unroll
      for (int t = 0; t < 4; ++t)
        *(f32x4*)&og[(t * 16 + lr) * 256 + w * 32 + m * 16 + lg * 4] = pacc[m][t];
  }
}

extern "C" void kernel_launch(void* const* d_in, const int* in_sizes, int n_in,
                              void* d_out, int out_size, void* d_ws, size_t ws_size,
                              hipStream_t stream) {
  (void)in_sizes; (void)n_in; (void)out_size; (void)ws_size;
  const float* x      = (const float*)d_in[0];
  const float* mask   = (const float*)d_in[1];
  const float* qkv_w  = (const float*)d_in[2];
  const float* qkv_b  = (const float*)d_in[3];
  const float* proj_w = (const float*)d_in[4];
  const float* proj_b = (const float*)d_in[5];
  const float* rpb    = (const float*)d_in[6];
  const int*   rel    = (const int*)d_in[7];

  unsigned short* qkv_wb  = (unsigned short*)d_ws;                       // 393216 B
  unsigned short* proj_wb = (unsigned short*)((char*)d_ws + 393216);     // 131072 B
  float*          rpe     = (float*)((char*)d_ws + 524288);              // 131072 B
  float*          qkv_bs  = (float*)((char*)d_ws + 655360);              // 3072 B
  float*          out     = (float*)d_out;

  prep_kernel<<<dim3(1155), dim3(256), 0, stream>>>(qkv_w, proj_w, rpb, rel, qkv_b,
                                                    qkv_wb, proj_wb, rpe, qkv_bs);
  win_attn_kernel<<<dim3(4096), dim3(512), 0, stream>>>(x, mask, qkv_wb, qkv_bs,
                                                        proj_wb, proj_b, rpe, out);
}